// Round 2
// baseline (743.620 us; speedup 1.0000x reference)
//
#include <hip/hip_runtime.h>

// ---------------------------------------------------------------------------
// EdgeLLMAttentionTRTNative: fused qkv-proj + rmsnorm + rope + cache update +
// GQA causal attention (group-summed) + o-proj.   I/O is FP32 (per reference);
// compute internally in bf16 MFMA with fp32 accumulation.
//
// Shapes: B=2 Q=1024 PAST=1024 MAXC=4096 H=32 HKV=8 D=128 HID=4096
// d_out (fp32) = [attn (2,1024,4096) | present_k (2,8,4096,128) | present_v]
// ---------------------------------------------------------------------------

typedef __bf16 bf16;
typedef __attribute__((ext_vector_type(8))) __bf16 bf16x8;
typedef __attribute__((ext_vector_type(4))) float f32x4;
typedef __attribute__((ext_vector_type(4))) unsigned int u32x4;

#define NB 2
#define NQ 1024
#define PAST 1024
#define MAXC 4096
#define NH 32
#define NKV 8
#define HD 128
#define HID 4096
#define SEQK 2048          // PAST + NQ
#define QKV_N 6144         // (H + 2*HKV) * D
#define SCALE 0.08838834764831845f
#define LOG2E 1.4426950408889634f

// ---------------------------------------------------------------------------
// GEMM:  C[M,N] = A[M,K](fp32) * Bt[N,K](bf16)^T, fp32 accum.
// 128x128 tile, BK=32, 4 waves, 16x16x32 bf16 MFMA. A converted fp32->bf16
// during LDS staging. LDS stride 40 bf16 (2-way bank alias = free, m136).
// ---------------------------------------------------------------------------
template <bool F32OUT>
__global__ __launch_bounds__(256) void gemm_a32(const float* __restrict__ A,
                                                const bf16* __restrict__ Bt,
                                                void* __restrict__ Cv,
                                                int M, int N, int K) {
    __shared__ bf16 As[128 * 40];
    __shared__ bf16 Bs[128 * 40];
    const int tid  = threadIdx.x;
    const int lane = tid & 63;
    const int wv   = tid >> 6;
    const int wm   = wv >> 1, wn = wv & 1;
    const int l15  = lane & 15, quad = lane >> 4;
    const int rowBase = blockIdx.y * 128;
    const int colBase = blockIdx.x * 128;

    f32x4 acc[4][4];
#pragma unroll
    for (int i = 0; i < 4; i++)
#pragma unroll
        for (int j = 0; j < 4; j++) acc[i][j] = (f32x4){0.f, 0.f, 0.f, 0.f};

    const int srow = tid >> 2;        // 0..63
    const int scol = (tid & 3) * 8;   // 0,8,16,24

    for (int k0 = 0; k0 < K; k0 += 32) {
#pragma unroll
        for (int i = 0; i < 2; i++) {
            const int r = srow + i * 64;
            const f32x4* ap = (const f32x4*)&A[(long)(rowBase + r) * K + k0 + scol];
            const f32x4 a0 = ap[0], a1 = ap[1];
            bf16x8 av;
#pragma unroll
            for (int j = 0; j < 4; j++) { av[j] = (bf16)a0[j]; av[4 + j] = (bf16)a1[j]; }
            *(bf16x8*)&As[r * 40 + scol] = av;
            *(u32x4*)&Bs[r * 40 + scol] =
                *(const u32x4*)&Bt[(long)(colBase + r) * K + k0 + scol];
        }
        __syncthreads();
        bf16x8 af[4], bfr[4];
#pragma unroll
        for (int mi = 0; mi < 4; mi++)
            af[mi] = *(const bf16x8*)&As[(wm * 64 + mi * 16 + l15) * 40 + quad * 8];
#pragma unroll
        for (int ni = 0; ni < 4; ni++)
            bfr[ni] = *(const bf16x8*)&Bs[(wn * 64 + ni * 16 + l15) * 40 + quad * 8];
#pragma unroll
        for (int mi = 0; mi < 4; mi++)
#pragma unroll
            for (int ni = 0; ni < 4; ni++)
                acc[mi][ni] = __builtin_amdgcn_mfma_f32_16x16x32_bf16(
                    af[mi], bfr[ni], acc[mi][ni], 0, 0, 0);
        __syncthreads();
    }
    // C/D layout: col = lane&15, row = quad*4 + reg  (m89-verified)
#pragma unroll
    for (int mi = 0; mi < 4; mi++)
#pragma unroll
        for (int r = 0; r < 4; r++) {
            const int row = rowBase + wm * 64 + mi * 16 + quad * 4 + r;
#pragma unroll
            for (int ni = 0; ni < 4; ni++) {
                const int col = colBase + wn * 64 + ni * 16 + l15;
                if (F32OUT) ((float*)Cv)[(long)row * N + col] = acc[mi][ni][r];
                else        ((bf16*)Cv)[(long)row * N + col] = (bf16)acc[mi][ni][r];
            }
        }
}

// ---------------------------------------------------------------------------
// Transpose + convert: out(C,R) bf16 = in(R,C) fp32 transposed.
// ---------------------------------------------------------------------------
__global__ __launch_bounds__(256) void transpose_f2b(const float* __restrict__ in,
                                                     bf16* __restrict__ out,
                                                     int R, int C) {
    __shared__ bf16 t[64][72];
    const int r0 = blockIdx.y * 64, c0 = blockIdx.x * 64;
    const int tid = threadIdx.x;
    const int lr = tid >> 3;          // 0..31
    const int lc = (tid & 7) * 8;     // 0..56
#pragma unroll
    for (int i = 0; i < 2; i++) {
        const f32x4* p = (const f32x4*)&in[(long)(r0 + lr + i * 32) * C + c0 + lc];
        const f32x4 v0 = p[0], v1 = p[1];
        bf16x8 v;
#pragma unroll
        for (int j = 0; j < 4; j++) { v[j] = (bf16)v0[j]; v[4 + j] = (bf16)v1[j]; }
        *(bf16x8*)&t[lr + i * 32][lc] = v;
    }
    __syncthreads();
#pragma unroll
    for (int i = 0; i < 2; i++) {
        const int oc = lr + i * 32;
        bf16x8 v;
#pragma unroll
        for (int j = 0; j < 8; j++) v[j] = t[lc + j][oc];
        *(bf16x8*)&out[(long)(c0 + oc) * R + r0 + lc] = v;
    }
}

// ---------------------------------------------------------------------------
// Batched bf16->bf16 transpose (used for V-present -> V^T).
// ---------------------------------------------------------------------------
__global__ __launch_bounds__(256) void transpose_bf16(const bf16* __restrict__ in,
                                                      bf16* __restrict__ out,
                                                      int R, int C,
                                                      long inBS, long outBS) {
    __shared__ bf16 t[64][72];
    in  += (long)blockIdx.z * inBS;
    out += (long)blockIdx.z * outBS;
    const int r0 = blockIdx.y * 64, c0 = blockIdx.x * 64;
    const int tid = threadIdx.x;
    const int lr = tid >> 3;
    const int lc = (tid & 7) * 8;
#pragma unroll
    for (int i = 0; i < 2; i++)
        *(u32x4*)&t[lr + i * 32][lc] =
            *(const u32x4*)&in[(long)(r0 + lr + i * 32) * C + c0 + lc];
    __syncthreads();
#pragma unroll
    for (int i = 0; i < 2; i++) {
        const int oc = lr + i * 32;
        bf16x8 v;
#pragma unroll
        for (int j = 0; j < 8; j++) v[j] = t[lc + j][oc];
        *(bf16x8*)&out[(long)(c0 + oc) * R + r0 + lc] = v;
    }
}

// ---------------------------------------------------------------------------
// Convert first SEQK rows of fp32 k/v caches to compact bf16 buffers.
// grid (128, 16, 2): z=0 -> K, z=1 -> V.  (New rows overwritten later.)
// ---------------------------------------------------------------------------
__global__ void cache_to_bf16(const float* __restrict__ kc, const float* __restrict__ vc,
                              bf16* __restrict__ kb, bf16* __restrict__ vb) {
    const int bh = blockIdx.y;  // b*NKV+hk
    const long idx = ((long)blockIdx.x * 256 + threadIdx.x) * 8;  // < SEQK*HD
    const float* src = (blockIdx.z ? vc : kc) + (long)bh * MAXC * HD + idx;
    bf16* dst = (blockIdx.z ? vb : kb) + (long)bh * SEQK * HD + idx;
    const f32x4 a = *(const f32x4*)src;
    const f32x4 b = *(const f32x4*)(src + 4);
    bf16x8 v;
#pragma unroll
    for (int j = 0; j < 4; j++) { v[j] = (bf16)a[j]; v[4 + j] = (bf16)b[j]; }
    *(bf16x8*)dst = v;
}

// ---------------------------------------------------------------------------
// Per (b,q,head48): RMSNorm (q,k), RoPE (q,k), scatter.
// 1 wave; lane l owns dims l and l+64 (the RoPE pair).
// q -> qbuf (bf16, pre-scaled); k -> out_k (fp32 cache) + kb (bf16);
// v -> out_v (fp32 cache) + vb (bf16 row-major present).
// ---------------------------------------------------------------------------
__global__ void qkv_post(const bf16* __restrict__ qkv, const float* __restrict__ cs,
                         const int* __restrict__ kvstart,
                         const float* __restrict__ qw, const float* __restrict__ kw,
                         bf16* __restrict__ qbuf, float* __restrict__ outk,
                         float* __restrict__ outv, bf16* __restrict__ kb,
                         bf16* __restrict__ vb) {
    const int h = blockIdx.x;   // 0..47: [0,32) q, [32,40) k, [40,48) v
    const int q = blockIdx.y;
    const int b = blockIdx.z;
    const int l = threadIdx.x;  // 0..63
    const bf16* x = qkv + (long)(b * NQ + q) * QKV_N + h * HD;
    float x1 = (float)x[l], x2 = (float)x[l + 64];
    const int pos = kvstart[b] + q;
    if (h < 40) {
        float sq = x1 * x1 + x2 * x2;
#pragma unroll
        for (int m = 32; m >= 1; m >>= 1) sq += __shfl_xor(sq, m);
        const float rr = rsqrtf(sq * (1.0f / 128.0f) + 1e-6f);
        const float w1 = (h < 32) ? qw[l] : kw[l];
        const float w2 = (h < 32) ? qw[l + 64] : kw[l + 64];
        const float y1 = x1 * rr * w1;
        const float y2 = x2 * rr * w2;
        const float c = cs[(long)pos * HD + l];
        const float s = cs[(long)pos * HD + 64 + l];
        const float o1 = y1 * c - y2 * s;
        const float o2 = y2 * c + y1 * s;
        if (h < 32) {  // fold softmax scale into q
            bf16* dst = qbuf + ((long)(b * NH + h) * NQ + q) * HD;
            dst[l] = (bf16)(o1 * SCALE);
            dst[l + 64] = (bf16)(o2 * SCALE);
        } else {
            const int hk = h - 32;
            float* df = outk + ((long)(b * NKV + hk) * MAXC + pos) * HD;
            df[l] = o1; df[l + 64] = o2;
            bf16* db = kb + ((long)(b * NKV + hk) * SEQK + pos) * HD;
            db[l] = (bf16)o1; db[l + 64] = (bf16)o2;
        }
    } else {
        const int hk = h - 40;
        float* df = outv + ((long)(b * NKV + hk) * MAXC + pos) * HD;
        df[l] = x1; df[l + 64] = x2;
        bf16* db = vb + ((long)(b * NKV + hk) * SEQK + pos) * HD;
        db[l] = (bf16)x1; db[l + 64] = (bf16)x2;
    }
}

// ---------------------------------------------------------------------------
// Flash attention: block = (qt, h, b), Q-tile 128 (4 waves x 2 strips of 16
// rows). 64-key K/V tiles in LDS; online softmax; P LDS round-trip (m120).
// q pre-scaled by SCALE.  kb: (b,hk,SEQK,HD) bf16; vt: (b,hk,HD,SEQK) bf16.
// ---------------------------------------------------------------------------
__global__ __launch_bounds__(256) void attn_fwd(const bf16* __restrict__ qbuf,
                                                const bf16* __restrict__ kb,
                                                const bf16* __restrict__ vt,
                                                bf16* __restrict__ oheads) {
    const int qt = blockIdx.x;   // 0..7
    const int h  = blockIdx.y;   // 0..31
    const int b  = blockIdx.z;
    const int hk = h >> 2;       // GQA: 4 query heads per kv head
    const int tid = threadIdx.x;
    const int lane = tid & 63, wv = tid >> 6;
    const int l15 = lane & 15, quad = lane >> 4;

    __shared__ bf16 Ks[64][136];   // keys x d   (+8 pad)
    __shared__ bf16 Vs[128][72];   // d x keys   (+8 pad)
    __shared__ bf16 Ps[4][32][72]; // per-wave P (+8 pad)

    const int qb = qt * 128 + wv * 32;

    bf16x8 aq[2][4];
#pragma unroll
    for (int ss = 0; ss < 2; ss++) {
        const bf16* qp = qbuf + ((long)(b * NH + h) * NQ + qb + ss * 16 + l15) * HD + quad * 8;
#pragma unroll
        for (int kc = 0; kc < 4; kc++) aq[ss][kc] = *(const bf16x8*)(qp + kc * 32);
    }

    f32x4 o[2][8];
    float m_[2][4], l_[2][4];
#pragma unroll
    for (int ss = 0; ss < 2; ss++) {
#pragma unroll
        for (int dt = 0; dt < 8; dt++) o[ss][dt] = (f32x4){0.f, 0.f, 0.f, 0.f};
#pragma unroll
        for (int r = 0; r < 4; r++) { m_[ss][r] = -1e30f; l_[ss][r] = 0.f; }
    }

    const long kcb = (long)(b * NKV + hk) * SEQK * HD;
    const long vtb = (long)(b * NKV + hk) * HD * (long)SEQK;
    const int ntiles = (qt * 128 + 127 + PAST + 64) >> 6;   // exact causal cover

    for (int t = 0; t < ntiles; t++) {
        const int k0 = t * 64;
#pragma unroll
        for (int i = 0; i < 4; i++) {   // stage K (64x128) and V^T (128x64)
            const int c = tid + i * 256;
            const int kr = c >> 4, c8 = (c & 15) * 8;
            *(bf16x8*)&Ks[kr][c8] = *(const bf16x8*)&kb[kcb + (long)(k0 + kr) * HD + c8];
            const int vr = c >> 3, v8 = (c & 7) * 8;
            *(bf16x8*)&Vs[vr][v8] = *(const bf16x8*)&vt[vtb + (long)vr * SEQK + k0 + v8];
        }
        __syncthreads();

#pragma unroll
        for (int ss = 0; ss < 2; ss++) {
            const int rbase = qb + ss * 16;
            f32x4 s[4];
#pragma unroll
            for (int nk = 0; nk < 4; nk++) s[nk] = (f32x4){0.f, 0.f, 0.f, 0.f};
#pragma unroll
            for (int kc = 0; kc < 4; kc++)
#pragma unroll
                for (int nk = 0; nk < 4; nk++) {
                    const bf16x8 bk = *(const bf16x8*)&Ks[nk * 16 + l15][kc * 32 + quad * 8];
                    s[nk] = __builtin_amdgcn_mfma_f32_16x16x32_bf16(aq[ss][kc], bk, s[nk], 0, 0, 0);
                }
            // causal: key > qrow + PAST  ->  -1e30
#pragma unroll
            for (int nk = 0; nk < 4; nk++) {
                const int key = k0 + nk * 16 + l15;
#pragma unroll
                for (int r = 0; r < 4; r++)
                    if (key > rbase + quad * 4 + r + PAST) s[nk][r] = -1e30f;
            }
            // online softmax; each row lives in a 16-lane group
#pragma unroll
            for (int r = 0; r < 4; r++) {
                float mx = fmaxf(fmaxf(s[0][r], s[1][r]), fmaxf(s[2][r], s[3][r]));
                mx = fmaxf(mx, __shfl_xor(mx, 1));
                mx = fmaxf(mx, __shfl_xor(mx, 2));
                mx = fmaxf(mx, __shfl_xor(mx, 4));
                mx = fmaxf(mx, __shfl_xor(mx, 8));
                const float mn = fmaxf(m_[ss][r], mx);
                const float alpha = exp2f((m_[ss][r] - mn) * LOG2E);
                float sum = 0.f;
#pragma unroll
                for (int nk = 0; nk < 4; nk++) {
                    const float p = exp2f((s[nk][r] - mn) * LOG2E);
                    s[nk][r] = p;
                    sum += p;
                }
                sum += __shfl_xor(sum, 1);
                sum += __shfl_xor(sum, 2);
                sum += __shfl_xor(sum, 4);
                sum += __shfl_xor(sum, 8);
                l_[ss][r] = l_[ss][r] * alpha + sum;
                m_[ss][r] = mn;
#pragma unroll
                for (int dt = 0; dt < 8; dt++) o[ss][dt][r] *= alpha;
            }
            // P: C-layout regs -> LDS rows (A-operand layout for PV)
#pragma unroll
            for (int nk = 0; nk < 4; nk++)
#pragma unroll
                for (int r = 0; r < 4; r++)
                    Ps[wv][ss * 16 + quad * 4 + r][nk * 16 + l15] = (bf16)s[nk][r];
        }
#pragma unroll
        for (int ss = 0; ss < 2; ss++)
#pragma unroll
            for (int kc = 0; kc < 2; kc++) {
                const bf16x8 ap = *(const bf16x8*)&Ps[wv][ss * 16 + l15][kc * 32 + quad * 8];
#pragma unroll
                for (int dt = 0; dt < 8; dt++) {
                    const bf16x8 bv = *(const bf16x8*)&Vs[dt * 16 + l15][kc * 32 + quad * 8];
                    o[ss][dt] = __builtin_amdgcn_mfma_f32_16x16x32_bf16(ap, bv, o[ss][dt], 0, 0, 0);
                }
            }
        __syncthreads();
    }

#pragma unroll
    for (int ss = 0; ss < 2; ss++) {
        float inv[4];
#pragma unroll
        for (int r = 0; r < 4; r++) inv[r] = 1.0f / l_[ss][r];
#pragma unroll
        for (int dt = 0; dt < 8; dt++)
#pragma unroll
            for (int r = 0; r < 4; r++) {
                const int row = qb + ss * 16 + quad * 4 + r;
                oheads[((long)(b * NH + h) * NQ + row) * HD + dt * 16 + l15] =
                    (bf16)(o[ss][dt][r] * inv[r]);
            }
    }
}

// ---------------------------------------------------------------------------
// sum over GQA groups: oheads (B,NH,Q,D) bf16 -> osum (B,Q,HKV*D) fp32
// ---------------------------------------------------------------------------
__global__ void group_sum(const bf16* __restrict__ oheads, float* __restrict__ osum) {
    const long e = ((long)blockIdx.x * 256 + threadIdx.x) * 8;
    const int b = (int)(e >> 20);
    const int rem = (int)(e & 1048575);
    const int q = rem >> 10;
    const int col = rem & 1023;
    const int hk = col >> 7;
    const int d = col & 127;
    float acc[8] = {0.f, 0.f, 0.f, 0.f, 0.f, 0.f, 0.f, 0.f};
#pragma unroll
    for (int g = 0; g < 4; g++) {
        const bf16x8 v = *(const bf16x8*)
            &oheads[((long)(b * NH + hk * 4 + g) * NQ + q) * HD + d];
#pragma unroll
        for (int j = 0; j < 8; j++) acc[j] += (float)v[j];
    }
    f32x4 r0, r1;
#pragma unroll
    for (int j = 0; j < 4; j++) { r0[j] = acc[j]; r1[j] = acc[4 + j]; }
    *(f32x4*)&osum[e] = r0;
    *(f32x4*)&osum[e + 4] = r1;
}

// ---------------------------------------------------------------------------
extern "C" void kernel_launch(void* const* d_in, const int* in_sizes, int n_in,
                              void* d_out, int out_size, void* d_ws, size_t ws_size,
                              hipStream_t stream) {
    const float* hidden  = (const float*)d_in[0];
    const float* kc_in   = (const float*)d_in[1];
    const float* vc_in   = (const float*)d_in[2];
    const float* rope_cs = (const float*)d_in[3];
    const int*   kvstart = (const int*)d_in[5];
    const float* w_qkv   = (const float*)d_in[6];
    const float* w_o     = (const float*)d_in[7];
    const float* qnw     = (const float*)d_in[8];
    const float* knw     = (const float*)d_in[9];

    float* out_attn = (float*)d_out;            // 8,388,608 f32
    float* out_k    = out_attn + 8388608L;      // 8,388,608 f32
    float* out_v    = out_k + 8388608L;         // 8,388,608 f32

    // d_out scratch (all regions rewritten before their real contents land):
    char* ob = (char*)d_out;
    bf16* qbuf  = (bf16*)ob;                    // 16,777,216 B ) together exactly
    bf16* kb16  = (bf16*)(ob + 16777216);       //  8,388,608 B ) fill the attn
    bf16* vtb16 = (bf16*)(ob + 25165824);       //  8,388,608 B ) region (33.5MB)
    bf16* wqkvT = (bf16*)(ob + 33554432);       // 50,331,648 B, dead before memcpys

    char* ws = (char*)d_ws;                     // total use: 32 MiB
    bf16*  qkvb   = (bf16*)ws;                  // 25,165,824 B
    bf16*  vpb16  = (bf16*)(ws + 25165824);     //  8,388,608 B
    bf16*  oheads = (bf16*)ws;                  // 16,777,216 B (qkvb dead)
    float* osum   = (float*)(ws + 16777216);    //  8,388,608 B (qkvb dead)
    bf16*  woT    = (bf16*)(ws + 25165824);     //  8,388,608 B (vpb16 dead)

    // 1. w_qkv (4096,6144) f32 -> wqkvT (6144,4096) bf16   [d_out scratch]
    transpose_f2b<<<dim3(96, 64), 256, 0, stream>>>(w_qkv, wqkvT, HID, QKV_N);
    // 2. qkv = hidden @ w_qkv   (bf16 out)
    gemm_a32<false><<<dim3(48, 16), 256, 0, stream>>>(hidden, wqkvT, qkvb, 2048, QKV_N, HID);
    // 3. old caches -> d_out (fp32, full 4096 rows)
    hipMemcpyAsync(out_k, kc_in, 33554432, hipMemcpyDeviceToDevice, stream);
    hipMemcpyAsync(out_v, vc_in, 33554432, hipMemcpyDeviceToDevice, stream);
    // 4. first 2048 cache rows -> compact bf16 (new rows overwritten in 5)
    cache_to_bf16<<<dim3(128, 16, 2), 256, 0, stream>>>(kc_in, vc_in, kb16, vpb16);
    // 5. rmsnorm + rope + scatter
    qkv_post<<<dim3(48, NQ, NB), 64, 0, stream>>>(qkvb, rope_cs, kvstart, qnw, knw,
                                                  qbuf, out_k, out_v, kb16, vpb16);
    // 6. V present (2048,128) -> V^T (128,2048) per (b,hk)
    transpose_bf16<<<dim3(2, 32, 16), 256, 0, stream>>>(vpb16, vtb16, SEQK, HD,
                                                        (long)SEQK * HD, (long)SEQK * HD);
    // 7. flash attention -> per-head O (bf16)
    attn_fwd<<<dim3(8, NH, NB), 256, 0, stream>>>(qbuf, kb16, vtb16, oheads);
    // 8. sum over GQA groups -> (B,Q,1024) fp32
    group_sum<<<dim3(1024), 256, 0, stream>>>(oheads, osum);
    // 9. w_o (1024,4096) f32 -> woT (4096,1024) bf16
    transpose_f2b<<<dim3(64, 16), 256, 0, stream>>>(w_o, woT, 1024, HID);
    // 10. attn_output = osum @ w_o -> d_out (fp32)
    gemm_a32<true><<<dim3(32, 16), 256, 0, stream>>>(osum, woT, out_attn, 2048, HID, 1024);
}